// Round 1
// 469.954 us; speedup vs baseline: 1.3828x; 1.3828x over previous
//
#include <hip/hip_runtime.h>
#include <hip/hip_bf16.h>
#include <math.h>

#define BATCH  8
#define NHEADS 8
#define KW     31
#define W      16384

// ---- workspace byte offsets ----
// floats at base: qWk [256][8] (2048 f), qWk_b [8], rpe_exp [8][31]
#define WS_QWKB 2048
#define WS_RPE  2056
#define OFF_WVH 9216                       // Wv bf16 [256][256]  (131072 B)
#define OFF_WOH (OFF_WVH + 131072)         // Wo bf16 [256][256]
#define OFF_CE  (OFF_WOH + 131072)         // cost_exp fp32 [NB][8][W]
// runtime-sized after OFF_CE:  vc fp32 [NB][W][256], u bf16 [NB][W][2][256]

typedef __attribute__((ext_vector_type(8))) short  short8;
typedef __attribute__((ext_vector_type(4))) float  f32x4;

__device__ __forceinline__ float f4c(const float4& v, int i) {
  switch (i) { case 0: return v.x; case 1: return v.y; case 2: return v.z; default: return v.w; }
}
__device__ __forceinline__ unsigned short f2bf(float f) {
  union { __hip_bfloat16 h; unsigned short u; } cv; cv.h = __float2bfloat16(f); return cv.u;
}
__device__ __forceinline__ float bf2f(unsigned short u) {
  union { __hip_bfloat16 h; unsigned short u; } cv; cv.u = u; return __bfloat162float(cv.h);
}

// ---------------------------------------------------------------- prep ------
// block 0: qWk [256][8], qWk_b[8], rpe_exp; blocks 1-4: Wv->bf16; 5-8: Wo->bf16
__global__ __launch_bounds__(256) void prep_kernel(
    const float* __restrict__ query, const float* __restrict__ Wk,
    const float* __restrict__ Wkb, const float* __restrict__ rpe,
    const float* __restrict__ Wv, const float* __restrict__ Wo,
    float* __restrict__ ws, unsigned short* __restrict__ WvH,
    unsigned short* __restrict__ WoH) {
  int t = threadIdx.x, bid = blockIdx.x;
  if (bid == 0) {
    __shared__ float q_l[256];
    float qv = query[t];
    float ss = qv * qv;
    #pragma unroll
    for (int m = 16; m >= 1; m >>= 1) ss += __shfl_xor(ss, m, 32);
    qv = qv / (sqrtf(ss) + 1e-6f) * 0.17677669529663687f;  // /(norm+1e-6)/sqrt(32)
    q_l[t] = qv;
    __syncthreads();
    const float* wr = Wk + (size_t)t * 256;
    #pragma unroll
    for (int h = 0; h < 8; ++h) {
      float s = 0.f;
      #pragma unroll
      for (int d = 0; d < 32; ++d) s = fmaf(q_l[h*32 + d], wr[h*32 + d], s);
      ws[t*8 + h] = s;
    }
    float pb = Wkb[t] * q_l[t];
    #pragma unroll
    for (int m = 16; m >= 1; m >>= 1) pb += __shfl_xor(pb, m, 32);
    if ((t & 31) == 0) ws[WS_QWKB + (t >> 5)] = pb;
    if (t < NHEADS * KW) ws[WS_RPE + t] = __expf(rpe[t]);
  } else {
    const float* src = (bid <= 4) ? Wv : Wo;
    unsigned short* dst = (bid <= 4) ? WvH : WoH;
    int seg = (bid - 1) & 3;
    int base4 = seg * 4096;   // float4 index base (16384 floats per segment)
    #pragma unroll
    for (int it = 0; it < 16; ++it) {
      int i4 = base4 + t + 256 * it;
      float4 v = ((const float4*)src)[i4];
      ushort4 o;
      o.x = f2bf(v.x); o.y = f2bf(v.y); o.z = f2bf(v.z); o.w = f2bf(v.w);
      ((ushort4*)dst)[i4] = o;
    }
  }
}

// ---------------------------------------------- K2: fused transpose+cost+V --
// per (64-w tile, batch): transpose x to LDS, cost->ce, in-place bf16 hi/lo
// split in LDS, MFMA v = Wv.x, scale by ce (+bias), write vc fp32 [w][256].
// Replaces the old transpose + gemm<0> pair; xT never touches HBM.
__global__ __launch_bounds__(256, 2) void xv_kernel(
    const float* __restrict__ x, const float* __restrict__ wsf,
    const unsigned short* __restrict__ A,   // WvH bf16 [256][256]
    const float* __restrict__ bias,         // to_v bias
    float* __restrict__ ceout, float* __restrict__ vcout, int b0) {
  __shared__ float xs[64 * 260];    // 66,560 B; row w = 1040 B:
                                    //   phase A: 256 fp32 chans
                                    //   phase B: 256 hi bf16 | 256 lo bf16 (in place)
  __shared__ float cbuf[2048];      // cost partial exchange
  __shared__ float ceL[512];        // ce[h][w]
  __shared__ float biasL[256];

  int t = threadIdx.x;
  int bb = blockIdx.y, b = b0 + bb;
  int w0 = blockIdx.x * 64;
  biasL[t] = bias[t];

  // P1: load x[D][w] tiles, 4x4 register transpose, write xs[w][D] fp32
  {
    int rr = t >> 4, c2 = t & 15;
    #pragma unroll
    for (int db = 0; db < 4; ++db) {
      float4 v0 = *(const float4*)(x + ((size_t)b*256 + db*64 + rr*4 + 0)*W + w0 + c2*4);
      float4 v1 = *(const float4*)(x + ((size_t)b*256 + db*64 + rr*4 + 1)*W + w0 + c2*4);
      float4 v2 = *(const float4*)(x + ((size_t)b*256 + db*64 + rr*4 + 2)*W + w0 + c2*4);
      float4 v3 = *(const float4*)(x + ((size_t)b*256 + db*64 + rr*4 + 3)*W + w0 + c2*4);
      #pragma unroll
      for (int i = 0; i < 4; ++i) {
        float4 tv = make_float4(f4c(v0,i), f4c(v1,i), f4c(v2,i), f4c(v3,i));
        *(float4*)&xs[(c2*4 + i)*260 + db*64 + rr*4] = tv;
      }
    }
  }
  __syncthreads();

  int w = t & 63, q = t >> 6;
  int qu = __builtin_amdgcn_readfirstlane(q);

  // P2a: pull this thread's 64-chan run into regs, accumulate cost partials
  f32x4 xr[16];
  {
    const float* xrow = &xs[w*260 + qu*64];
    #pragma unroll
    for (int i = 0; i < 16; ++i) xr[i] = *(const f32x4*)(xrow + 4*i);
    float ca[8] = {0,0,0,0,0,0,0,0};
    const float* qkb = wsf + (size_t)qu*64*8;
    #pragma unroll
    for (int k8 = 0; k8 < 8; ++k8) {
      const float* qr = qkb + 64*k8;
      #pragma unroll
      for (int e = 0; e < 4; ++e) {
        #pragma unroll
        for (int h = 0; h < 8; ++h) {
          ca[h] = fmaf(xr[2*k8][e],   qr[e*8 + h],     ca[h]);
          ca[h] = fmaf(xr[2*k8+1][e], qr[(e+4)*8 + h], ca[h]);
        }
      }
    }
    #pragma unroll
    for (int h = 0; h < 8; ++h) cbuf[t*8 + h] = ca[h];
  }
  __syncthreads();   // all fp32 reads of xs done before in-place overwrite

  // P2b: in-place hi/lo bf16 split: row w -> hi[256] @ +0, lo[256] @ +512 B
  {
    unsigned short* hrow = (unsigned short*)xs + w*520 + qu*64;
    #pragma unroll
    for (int k8 = 0; k8 < 8; ++k8) {
      short8 hs, ls;
      #pragma unroll
      for (int e = 0; e < 4; ++e) {
        float a0 = xr[2*k8][e], a1 = xr[2*k8+1][e];
        unsigned short h0 = f2bf(a0), h1 = f2bf(a1);
        hs[e]   = (short)h0;  hs[e+4] = (short)h1;
        ls[e]   = (short)f2bf(a0 - bf2f(h0));
        ls[e+4] = (short)f2bf(a1 - bf2f(h1));
      }
      *(short8*)(hrow + 8*k8)       = hs;
      *(short8*)(hrow + 256 + 8*k8) = ls;
    }
  }
  __syncthreads();

  // P3: reduce cost partials, exp, -> ceL + global ce
  #pragma unroll
  for (int s = 0; s < 2; ++s) {
    int idx = t + 256*s;
    int h = idx >> 6, ww = idx & 63;
    float sum = cbuf[ww*8 + h] + cbuf[(64+ww)*8 + h] + cbuf[(128+ww)*8 + h]
              + cbuf[(192+ww)*8 + h] + wsf[WS_QWKB + h];
    float ce = __expf(sum);
    ceL[h*64 + ww] = ce;
    ceout[((size_t)bb*8 + h)*W + w0 + ww] = ce;
  }
  __syncthreads();

  // P4: MFMA GEMM  v[256 o][64 w] = Wv . x  (hi + lo)
  int wid = t >> 6, quad = (t >> 4) & 3, m = t & 15;
  f32x4 acc[4][4];
  #pragma unroll
  for (int j = 0; j < 4; ++j)
    #pragma unroll
    for (int c = 0; c < 4; ++c) acc[j][c] = (f32x4){0.f, 0.f, 0.f, 0.f};

  const unsigned short* xsu = (const unsigned short*)xs;
  #pragma unroll
  for (int kk = 0; kk < 8; ++kk) {
    int ko = kk*32 + quad*8;
    short8 a[4], bh[4], bl[4];
    #pragma unroll
    for (int j = 0; j < 4; ++j)
      a[j] = *(const short8*)(A + (size_t)(64*wid + 16*j + m)*256 + ko);
    #pragma unroll
    for (int c = 0; c < 4; ++c) {
      int rw = 16*c + m;
      bh[c] = *(const short8*)(xsu + rw*520 + ko);
      bl[c] = *(const short8*)(xsu + rw*520 + 256 + ko);
    }
    #pragma unroll
    for (int j = 0; j < 4; ++j)
      #pragma unroll
      for (int c = 0; c < 4; ++c) {
        acc[j][c] = __builtin_amdgcn_mfma_f32_16x16x32_bf16(a[j], bh[c], acc[j][c], 0, 0, 0);
        acc[j][c] = __builtin_amdgcn_mfma_f32_16x16x32_bf16(a[j], bl[c], acc[j][c], 0, 0, 0);
      }
  }
  __syncthreads();   // B-reads of xs done before epilogue reuses it

  // P5: vc = ce[h][w] * (v + bias) -> xs [w][o] pitch 260 -> global fp32
  #pragma unroll
  for (int j = 0; j < 4; ++j) {
    int ob = 64*wid + 16*j + 4*quad;
    int h = (64*wid + 16*j) >> 5;
    #pragma unroll
    for (int c = 0; c < 4; ++c) {
      int wc = 16*c + m;
      float ce = ceL[h*64 + wc];
      f32x4 r;
      #pragma unroll
      for (int i = 0; i < 4; ++i) r[i] = (acc[j][c][i] + biasL[ob + i]) * ce;
      *(f32x4*)(xs + wc*260 + ob) = r;
    }
  }
  __syncthreads();
  {
    size_t rowbase = (size_t)bb*W + w0;
    int w2 = t >> 2;
    #pragma unroll
    for (int k = 0; k < 16; ++k) {
      int oq = (t & 3)*64 + 4*k;
      f32x4 v = *(const f32x4*)(xs + w2*260 + oq);
      *(f32x4*)(vcout + (rowbase + w2)*256 + oq) = v;
    }
  }
}

// ------------------------------------------------- K5: MFMA GEMM (out) ------
// C[o][w] = A(bf16 256x256) . B(hi+lo bf16, [w][hi256|lo256])
// MODE 1: out epilogue (+bias), write d_out [b][o][W]
template<int MODE>
__global__ __launch_bounds__(256, 2) void gemm_kernel(
    const unsigned short* __restrict__ A, const float* __restrict__ bias,
    const float* __restrict__ cost, unsigned short* Bact,
    float* outp, int b0) {
  __shared__ float smem[17408];     // staging (128 rows x 528B) / assembly
  __shared__ float ceL[512];
  __shared__ float biasL[256];
  unsigned short* smem_u = (unsigned short*)smem;

  int t = threadIdx.x;
  int bb = blockIdx.y;
  int w0 = blockIdx.x * 64;

  biasL[t] = bias[t];
  if (MODE == 0) {
    #pragma unroll
    for (int s = 0; s < 2; ++s) {
      int i = t + 256*s;
      ceL[i] = cost[((size_t)(bb*8 + (i >> 6)))*W + w0 + (i & 63)];
    }
  }
  // stage B tile: 64 w x 1024B (hi row, lo row) -> LDS rows pitch 264 ushort
  {
    const unsigned short* src = Bact + ((size_t)bb*W + w0)*512;
    #pragma unroll
    for (int it = 0; it < 16; ++it) {
      int idx = t + 256*it;
      int r = idx >> 5, col = (idx & 31) * 8;
      short8 v = *(const short8*)(src + (size_t)idx*8);
      *(short8*)(smem_u + r*264 + col) = v;
    }
  }
  __syncthreads();

  int wid = t >> 6, quad = (t >> 4) & 3, m = t & 15;
  f32x4 acc[4][4];
  #pragma unroll
  for (int j = 0; j < 4; ++j)
    #pragma unroll
    for (int c = 0; c < 4; ++c) acc[j][c] = (f32x4){0.f, 0.f, 0.f, 0.f};

  #pragma unroll
  for (int kk = 0; kk < 8; ++kk) {
    int ko = kk*32 + quad*8;
    short8 a[4], bh[4], bl[4];
    #pragma unroll
    for (int j = 0; j < 4; ++j)
      a[j] = *(const short8*)(A + (size_t)(64*wid + 16*j + m)*256 + ko);
    #pragma unroll
    for (int c = 0; c < 4; ++c) {
      int row = 2*(16*c + m);
      bh[c] = *(const short8*)(smem_u + row*264 + ko);
      bl[c] = *(const short8*)(smem_u + (row+1)*264 + ko);
    }
    #pragma unroll
    for (int j = 0; j < 4; ++j)
      #pragma unroll
      for (int c = 0; c < 4; ++c) {
        acc[j][c] = __builtin_amdgcn_mfma_f32_16x16x32_bf16(a[j], bh[c], acc[j][c], 0, 0, 0);
        acc[j][c] = __builtin_amdgcn_mfma_f32_16x16x32_bf16(a[j], bl[c], acc[j][c], 0, 0, 0);
      }
  }
  __syncthreads();

  if (MODE == 0) {
    // vc = ce[h][w] * (v + bias) -> smem [w][o] pitch 260 -> global fp32
    #pragma unroll
    for (int j = 0; j < 4; ++j) {
      int ob = 64*wid + 16*j + 4*quad;
      int h = (64*wid + 16*j) >> 5;
      #pragma unroll
      for (int c = 0; c < 4; ++c) {
        int w = 16*c + m;
        float ce = ceL[h*64 + w];
        f32x4 r;
        #pragma unroll
        for (int i = 0; i < 4; ++i) r[i] = (acc[j][c][i] + biasL[ob + i]) * ce;
        *(f32x4*)(smem + w*260 + ob) = r;
      }
    }
    __syncthreads();
    float* vcg = (float*)Bact;
    size_t rowbase = (size_t)bb*W + w0;
    int w = t >> 2;
    #pragma unroll
    for (int k = 0; k < 16; ++k) {
      int oq = (t & 3)*64 + 4*k;
      f32x4 v = *(const f32x4*)(smem + w*260 + oq);
      *(f32x4*)(vcg + (rowbase + w)*256 + oq) = v;
    }
  } else {
    // out = v + bias -> smem [o][w] pitch 68 -> d_out
    #pragma unroll
    for (int j = 0; j < 4; ++j) {
      int ob = 64*wid + 16*j + 4*quad;
      #pragma unroll
      for (int c = 0; c < 4; ++c) {
        int w = 16*c + m;
        #pragma unroll
        for (int i = 0; i < 4; ++i) smem[(ob + i)*68 + w] = acc[j][c][i] + biasL[ob + i];
      }
    }
    __syncthreads();
    float* og = outp + (size_t)(b0 + bb)*256*W;
    #pragma unroll
    for (int i = 0; i < 4; ++i) {
      int o = (t >> 2) + 64*i;
      int c4 = t & 3;
      #pragma unroll
      for (int k = 0; k < 4; ++k) {
        int w = (c4 + 4*k)*4;
        f32x4 v = *(const f32x4*)(smem + o*68 + w);
        *(f32x4*)(og + (size_t)o*W + w0 + w) = v;
      }
    }
  }
}

// ------------------------------------------------------- K4: conv -----------
// depthwise K=31 windowed sums of vc and ce; u = sum_v/sum_c -> bf16 hi/lo
__global__ __launch_bounds__(256, 2) void conv_kernel(
    const float* __restrict__ vc, const float* __restrict__ costexp,
    const float* __restrict__ rpe_ws, unsigned short* __restrict__ u) {
  __shared__ float vcl[94 * 132];   // [w'][128 d] fp32, pitch 132
  __shared__ float cel[8 * 96];     // ce halo
  __shared__ float rcl[8 * 64];     // 1/sum_c
  __shared__ float rpel[8 * 32];

  int t = threadIdx.x;
  int half = blockIdx.y, bb = blockIdx.z;
  int w0 = blockIdx.x * 64;

  rpel[t] = ((t & 31) < KW) ? rpe_ws[(t >> 5)*KW + (t & 31)] : 0.f;
  // stage ce halo [8][94]
  #pragma unroll
  for (int it = 0; it < 3; ++it) {
    int idx = t + 256*it;
    int h = idx / 96, c = idx % 96;
    if (h < 8) {
      int gw = w0 - 15 + c;
      cel[idx] = (c < 94 && gw >= 0 && gw < W) ? costexp[((size_t)bb*8 + h)*W + gw] : 0.f;
    }
  }
  // stage vc tile [94][128]
  #pragma unroll
  for (int it = 0; it < 12; ++it) {
    int idx = t + 256*it;
    int r = idx >> 5, c4 = (idx & 31)*4;
    if (r < 94) {
      int gw = w0 - 15 + r;
      float4 v = make_float4(0.f, 0.f, 0.f, 0.f);
      if (gw >= 0 && gw < W)
        v = *(const float4*)(vc + ((size_t)bb*W + gw)*256 + half*128 + c4);
      *(float4*)&vcl[r*132 + c4] = v;
    }
  }
  __syncthreads();

  // rc = 1/sum_c for all (h, w)
  #pragma unroll
  for (int s = 0; s < 2; ++s) {
    int idx = t + 256*s;
    int h = idx >> 6, w = idx & 63;
    float acc = 0.f;
    #pragma unroll
    for (int k = 0; k < KW; ++k) acc = fmaf(rpel[h*32 + k], cel[h*96 + w + k], acc);
    rcl[h*64 + w] = 1.0f / acc;
  }
  __syncthreads();

  int p = t & 63, g = t >> 6;
  int hh = half*4 + (p >> 4);
  float rp[KW];
  #pragma unroll
  for (int k = 0; k < KW; ++k) rp[k] = rpel[hh*32 + k];

  float ax[16], ay[16];
  #pragma unroll
  for (int i = 0; i < 16; ++i) { ax[i] = 0.f; ay[i] = 0.f; }
  #pragma unroll
  for (int s = 0; s < 46; ++s) {
    float2 v = *(const float2*)&vcl[(16*g + s)*132 + 2*p];
    #pragma unroll
    for (int i = 0; i < 16; ++i) {
      int k = s - i;
      if (k >= 0 && k < KW) {
        ax[i] = fmaf(rp[k], v.x, ax[i]);
        ay[i] = fmaf(rp[k], v.y, ay[i]);
      }
    }
  }
  #pragma unroll
  for (int i = 0; i < 16; ++i) {
    float rc = rcl[hh*64 + 16*g + i];
    float ux = ax[i] * rc, uy = ay[i] * rc;
    unsigned short hx = f2bf(ux), hy = f2bf(uy);
    unsigned short lx = f2bf(ux - bf2f(hx)), ly = f2bf(uy - bf2f(hy));
    unsigned short* ud = u + ((size_t)bb*W + w0 + 16*g + i)*512 + half*128 + 2*p;
    ushort2 hvv; hvv.x = hx; hvv.y = hy;
    ushort2 lvv; lvv.x = lx; lvv.y = ly;
    *(ushort2*)(ud)       = hvv;
    *(ushort2*)(ud + 256) = lvv;
  }
}

// ---------------------------------------------------------------- launch ----
extern "C" void kernel_launch(void* const* d_in, const int* in_sizes, int n_in,
                              void* d_out, int out_size, void* d_ws, size_t ws_size,
                              hipStream_t stream) {
  const float* x     = (const float*)d_in[0];
  const float* query = (const float*)d_in[1];
  const float* Wk    = (const float*)d_in[2];
  const float* Wkb   = (const float*)d_in[3];
  const float* rpe   = (const float*)d_in[4];
  const float* Wv    = (const float*)d_in[5];
  const float* tvb   = (const float*)d_in[6];
  const float* Wo    = (const float*)d_in[7];
  const float* tob   = (const float*)d_in[8];
  float* out = (float*)d_out;
  char* wsb  = (char*)d_ws;
  float* wsf = (float*)d_ws;

  unsigned short* WvH = (unsigned short*)(wsb + OFF_WVH);
  unsigned short* WoH = (unsigned short*)(wsb + OFF_WOH);

  // per-batch workspace: ce 512 KiB + vc 16 MiB + u 16 MiB
  const size_t per_b = (size_t)8*W*4 + (size_t)W*256*4 + (size_t)W*512*2;
  int NB = (int)((ws_size > OFF_CE) ? ((ws_size - OFF_CE) / per_b) : 1);
  if (NB > BATCH) NB = BATCH;
  if (NB < 1) NB = 1;

  float*          ceB = (float*)(wsb + OFF_CE);
  float*          vcB = (float*)(wsb + OFF_CE + (size_t)NB*8*W*4);
  unsigned short* uB  = (unsigned short*)(wsb + OFF_CE + (size_t)NB*8*W*4 + (size_t)NB*W*256*4);

  prep_kernel<<<9, 256, 0, stream>>>(query, Wk, Wkb, rpe, Wv, Wo, wsf, WvH, WoH);

  for (int b0 = 0; b0 < BATCH; b0 += NB) {
    int nb = (BATCH - b0 < NB) ? (BATCH - b0) : NB;
    xv_kernel<<<dim3(256, nb), 256, 0, stream>>>(x, wsf, WvH, tvb, ceB, vcB, b0);
    conv_kernel<<<dim3(256, 2, nb), 256, 0, stream>>>(vcB, ceB, wsf + WS_RPE, uB);
    gemm_kernel<1><<<dim3(256, nb), 256, 0, stream>>>(WoH, tob, nullptr, uB, out, b0);
  }
}